// Round 2
// baseline (1068.584 us; speedup 1.0000x reference)
//
#include <hip/hip_runtime.h>
#include <hip/hip_bf16.h>

// Grouped GEMM (ragged rows over 8 experts), w8a8-style dequant epilogue.
// out[m,n] = (sum_k a[m,k]*b[e(m),n,k]) * scale_a[m] * scale_b[e(m)]
// M=16384, K=2048, N=5632, E=8.  a,b f32 in HBM; compute in bf16 MFMA.

#define BM 128
#define BN 128
#define BK 64
#define NKSTEP (2048 / BK)

typedef __attribute__((ext_vector_type(4))) float f32x4;
typedef __attribute__((ext_vector_type(2))) unsigned int u32x2;
using frag_ab = __attribute__((ext_vector_type(8))) short;  // 8 bf16
using frag_cd = __attribute__((ext_vector_type(4))) float;  // 4 f32

// round-to-nearest-even f32 -> bf16, packed pair (x in low 16, y in high 16)
__device__ __forceinline__ unsigned int pack_bf2(float x, float y) {
  unsigned int ux = __float_as_uint(x);
  unsigned int uy = __float_as_uint(y);
  ux += 0x7fffu + ((ux >> 16) & 1u);
  uy += 0x7fffu + ((uy >> 16) & 1u);
  return (ux >> 16) | (uy & 0xffff0000u);
}

__global__ __launch_bounds__(256, 2)
void ggemm_kernel(const float* __restrict__ A,
                  const float* __restrict__ B,
                  const float* __restrict__ sa,
                  const float* __restrict__ sb,
                  const int* __restrict__ seg,
                  float* __restrict__ C) {
  constexpr int M = 16384, K = 2048, N = 5632, E = 8;
  constexpr int NT = N / BN;  // 44

  // XCD-aware bijective swizzle (nwg = 5632, % 8 == 0)
  const int nwg = (M / BM) * NT;
  int bid = blockIdx.x;
  int cpx = nwg >> 3;
  int sid = (bid & 7) * cpx + (bid >> 3);
  int mt = sid / NT, nt = sid % NT;
  int m0 = mt * BM, n0 = nt * BN;

  int tid = threadIdx.x;
  int lane = tid & 63;
  int wid = tid >> 6;
  int wr = (wid >> 1) * 64;  // wave's row offset in tile (2x2 wave grid)
  int wc = (wid & 1) * 64;   // wave's col offset
  int l16 = lane & 15, lhi = lane >> 4;

  // bf16 tiles, XOR-swizzled (T2): physical short off = (row*64+k) ^ ((row&7)<<3)
  __shared__ short smem[2][2][BM * BK];  // [buf][0=A,1=B] -> 64 KiB

  // staging: chunk c = tid + i*256 ; row = (tid>>4)+i*16 ; kc = (tid&15)*4
  const int s_kc = (tid & 15) * 4;
  const int s_row = tid >> 4;
  const float* Abase = A + (size_t)(m0 + s_row) * K + s_kc;

  f32x4 ar[8], br[8];

  for (int e = 0; e < E; ++e) {
    int rlo = max(m0, seg[e]);
    int rhi = min(m0 + BM, seg[e + 1]);
    if (rlo >= rhi) continue;
    const float* Bbase = B + (size_t)e * N * K + (size_t)(n0 + s_row) * K + s_kc;

    frag_cd acc[4][4];
#pragma unroll
    for (int i = 0; i < 4; ++i)
#pragma unroll
      for (int j = 0; j < 4; ++j) acc[i][j] = (frag_cd){0.f, 0.f, 0.f, 0.f};

    auto issue_loads = [&](int kt) {
#pragma unroll
      for (int i = 0; i < 8; ++i) {
        ar[i] = *(const f32x4*)(Abase + (size_t)i * 16 * K + kt * BK);
        br[i] = *(const f32x4*)(Bbase + (size_t)i * 16 * K + kt * BK);
      }
    };
    auto write_lds = [&](int buf) {
      short* pa = &smem[buf][0][0];
      short* pb = &smem[buf][1][0];
#pragma unroll
      for (int i = 0; i < 8; ++i) {
        int row = s_row + i * 16;
        int off = (row * BK + s_kc) ^ ((row & 7) << 3);
        u32x2 va, vb;
        va[0] = pack_bf2(ar[i][0], ar[i][1]);
        va[1] = pack_bf2(ar[i][2], ar[i][3]);
        vb[0] = pack_bf2(br[i][0], br[i][1]);
        vb[1] = pack_bf2(br[i][2], br[i][3]);
        *(u32x2*)(pa + off) = va;
        *(u32x2*)(pb + off) = vb;
      }
    };
    auto compute = [&](int buf) {
      const short* pa = &smem[buf][0][0];
      const short* pb = &smem[buf][1][0];
#pragma unroll
      for (int ks = 0; ks < 2; ++ks) {
        frag_ab af[4], bf[4];
#pragma unroll
        for (int i = 0; i < 4; ++i) {
          int row = wr + i * 16 + l16;
          int off = (row * BK + ks * 32 + lhi * 8) ^ ((row & 7) << 3);
          af[i] = *(const frag_ab*)(pa + off);
        }
#pragma unroll
        for (int j = 0; j < 4; ++j) {
          int row = wc + j * 16 + l16;
          int off = (row * BK + ks * 32 + lhi * 8) ^ ((row & 7) << 3);
          bf[j] = *(const frag_ab*)(pb + off);
        }
#pragma unroll
        for (int i = 0; i < 4; ++i)
#pragma unroll
          for (int j = 0; j < 4; ++j)
            acc[i][j] = __builtin_amdgcn_mfma_f32_16x16x32_bf16(
                af[i], bf[j], acc[i][j], 0, 0, 0);
      }
    };

    // prologue
    issue_loads(0);
    write_lds(0);
    __syncthreads();

    for (int kt = 0; kt < NKSTEP; ++kt) {
      int cur = kt & 1;
      bool more = (kt + 1 < NKSTEP);
      if (more) issue_loads(kt + 1);  // loads in flight under compute
      compute(cur);
      if (more) write_lds(cur ^ 1);   // waits vmcnt, writes other buffer
      __syncthreads();
    }

    // epilogue: dequant + masked store of rows [rlo, rhi)
    float sbe = sb[e];
#pragma unroll
    for (int i = 0; i < 4; ++i) {
#pragma unroll
      for (int r = 0; r < 4; ++r) {
        int grow = m0 + wr + i * 16 + lhi * 4 + r;
        if (grow >= rlo && grow < rhi) {
          float s = sa[grow] * sbe;
          float* Crow = C + (size_t)grow * N + n0 + wc;
#pragma unroll
          for (int j = 0; j < 4; ++j)
            Crow[j * 16 + l16] = acc[i][j][r] * s;
        }
      }
    }
  }
}

extern "C" void kernel_launch(void* const* d_in, const int* in_sizes, int n_in,
                              void* d_out, int out_size, void* d_ws, size_t ws_size,
                              hipStream_t stream) {
  const float* a = (const float*)d_in[0];
  const float* b = (const float*)d_in[1];
  const float* sa = (const float*)d_in[2];
  const float* sb = (const float*)d_in[3];
  const int* seg = (const int*)d_in[4];
  float* out = (float*)d_out;

  dim3 grid((16384 / BM) * (5632 / BN));  // 5632 blocks
  dim3 block(256);
  hipLaunchKernelGGL(ggemm_kernel, grid, block, 0, stream, a, b, sa, sb, seg, out);
}

// Round 3
// 751.255 us; speedup vs baseline: 1.4224x; 1.4224x over previous
//
#include <hip/hip_runtime.h>
#include <hip/hip_bf16.h>

// Grouped GEMM (ragged rows over 8 experts), w8a8-style dequant epilogue.
// out[m,n] = (sum_k a[m,k]*b[e(m),n,k]) * scale_a[m] * scale_b[e(m)]
// M=16384, K=2048, N=5632, E=8.
// R2: convert f32->bf16 once into d_ws, then m97-style gload_lds GEMM.

#define BM 128
#define BN 128
#define BK 64
#define NKSTEP (2048 / BK)

typedef __attribute__((ext_vector_type(4))) float f32x4;
typedef __attribute__((ext_vector_type(2))) unsigned int u32x2;
typedef __attribute__((ext_vector_type(4))) unsigned int u32x4;
using frag_ab = __attribute__((ext_vector_type(8))) short;  // 8 bf16
using frag_cd = __attribute__((ext_vector_type(4))) float;  // 4 f32

// round-to-nearest-even f32 -> bf16, packed pair (x low 16, y high 16)
__device__ __forceinline__ unsigned int pack_bf2(float x, float y) {
  unsigned int ux = __float_as_uint(x);
  unsigned int uy = __float_as_uint(y);
  ux += 0x7fffu + ((ux >> 16) & 1u);
  uy += 0x7fffu + ((uy >> 16) & 1u);
  return (ux >> 16) | (uy & 0xffff0000u);
}

__device__ __forceinline__ void gload_lds16(const void* g, void* lds) {
  __builtin_amdgcn_global_load_lds(
      (const __attribute__((address_space(1))) unsigned int*)g,
      (__attribute__((address_space(3))) unsigned int*)lds, 16, 0, 0);
}

// ---------------- convert pass: f32 -> bf16 into ws ----------------
__global__ __launch_bounds__(256)
void convert_kernel(const float* __restrict__ A, const float* __restrict__ B,
                    unsigned short* __restrict__ wa, unsigned short* __restrict__ wb) {
  constexpr long long NA = 16384LL * 2048;           // 33554432
  constexpr long long NB = 8LL * 5632 * 2048;        // 92274688
  constexpr long long NA8 = NA / 8;                  // 4194304
  constexpr long long NTOT = (NA + NB) / 8;          // 15728640
  for (long long c = (long long)blockIdx.x * 256 + threadIdx.x; c < NTOT;
       c += (long long)gridDim.x * 256) {
    const float* src;
    unsigned short* dst;
    long long off;
    if (c < NA8) { src = A; dst = wa; off = c * 8; }
    else         { src = B; dst = wb; off = (c - NA8) * 8; }
    f32x4 v0 = *(const f32x4*)(src + off);
    f32x4 v1 = *(const f32x4*)(src + off + 4);
    u32x4 o;
    o[0] = pack_bf2(v0[0], v0[1]);
    o[1] = pack_bf2(v0[2], v0[3]);
    o[2] = pack_bf2(v1[0], v1[1]);
    o[3] = pack_bf2(v1[2], v1[3]);
    *(u32x4*)(dst + off) = o;
  }
}

// ---------------- bf16 grouped GEMM (gload_lds staging) ----------------
__global__ __launch_bounds__(256, 2)
void ggemm_bf16(const unsigned short* __restrict__ A,
                const unsigned short* __restrict__ B,
                const float* __restrict__ sa,
                const float* __restrict__ sb,
                const int* __restrict__ seg,
                float* __restrict__ C) {
  constexpr int M = 16384, K = 2048, N = 5632, E = 8;
  constexpr int NT = N / BN;  // 44

  const int nwg = (M / BM) * NT;  // 5632, % 8 == 0
  int bid = blockIdx.x;
  int cpx = nwg >> 3;
  int sid = (bid & 7) * cpx + (bid >> 3);
  int mt = sid / NT, nt = sid % NT;
  int m0 = mt * BM, n0 = nt * BN;

  int tid = threadIdx.x;
  int lane = tid & 63;
  int w = tid >> 6;
  int wr = (w >> 1) * 64;
  int wc = (w & 1) * 64;
  int l16 = lane & 15, lhi = lane >> 4;

  // linear LDS [128][64] bf16 per operand (gload_lds needs linear dest)
  __shared__ unsigned short smem[2][2][BM * BK];  // 64 KiB

  // staging: wave w owns rows [w*32, w*32+32); instr i covers 8 rows.
  // per-lane global offset (shorts): row = w*32 + (lane>>3), col = (lane&7)*8
  const int s_row = w * 32 + (lane >> 3);
  const int s_col = (lane & 7) * 8;
  const unsigned short* Apl = A + (size_t)(m0 + s_row) * K + s_col;

  for (int e = 0; e < E; ++e) {
    int rlo = max(m0, seg[e]);
    int rhi = min(m0 + BM, seg[e + 1]);
    if (rlo >= rhi) continue;
    const unsigned short* Bpl = B + (size_t)e * N * K + (size_t)(n0 + s_row) * K + s_col;

    frag_cd acc[4][4];
#pragma unroll
    for (int i = 0; i < 4; ++i)
#pragma unroll
      for (int j = 0; j < 4; ++j) acc[i][j] = (frag_cd){0.f, 0.f, 0.f, 0.f};

    auto stage = [&](int buf, int kt) {
#pragma unroll
      for (int i = 0; i < 4; ++i) {
        gload_lds16(Apl + (size_t)i * 8 * K + kt * BK,
                    &smem[buf][0][(w * 32 + i * 8) * BK]);
        gload_lds16(Bpl + (size_t)i * 8 * K + kt * BK,
                    &smem[buf][1][(w * 32 + i * 8) * BK]);
      }
    };
    auto compute = [&](int buf) {
      const unsigned short* pa = &smem[buf][0][0];
      const unsigned short* pb = &smem[buf][1][0];
#pragma unroll
      for (int ks = 0; ks < 2; ++ks) {
        frag_ab af[4], bf[4];
#pragma unroll
        for (int i = 0; i < 4; ++i)
          af[i] = *(const frag_ab*)(pa + (wr + i * 16 + l16) * BK + ks * 32 + lhi * 8);
#pragma unroll
        for (int j = 0; j < 4; ++j)
          bf[j] = *(const frag_ab*)(pb + (wc + j * 16 + l16) * BK + ks * 32 + lhi * 8);
#pragma unroll
        for (int i = 0; i < 4; ++i)
#pragma unroll
          for (int j = 0; j < 4; ++j)
            acc[i][j] = __builtin_amdgcn_mfma_f32_16x16x32_bf16(
                af[i], bf[j], acc[i][j], 0, 0, 0);
      }
    };

    stage(0, 0);
    __syncthreads();  // compiler emits vmcnt(0) before barrier

    for (int kt = 0; kt < NKSTEP; ++kt) {
      int cur = kt & 1;
      if (kt + 1 < NKSTEP) stage(cur ^ 1, kt + 1);  // loads in flight over compute
      compute(cur);
      __syncthreads();
    }

    float sbe = sb[e];
#pragma unroll
    for (int i = 0; i < 4; ++i) {
#pragma unroll
      for (int r = 0; r < 4; ++r) {
        int grow = m0 + wr + i * 16 + lhi * 4 + r;
        if (grow >= rlo && grow < rhi) {
          float s = sa[grow] * sbe;
          float* Crow = C + (size_t)grow * N + n0 + wc;
#pragma unroll
          for (int j = 0; j < 4; ++j)
            Crow[j * 16 + l16] = acc[i][j][r] * s;
        }
      }
    }
  }
}

// ---------------- fallback: R2 f32-input kernel (unchanged) ----------------
__global__ __launch_bounds__(256, 2)
void ggemm_f32(const float* __restrict__ A, const float* __restrict__ B,
               const float* __restrict__ sa, const float* __restrict__ sb,
               const int* __restrict__ seg, float* __restrict__ C) {
  constexpr int M = 16384, K = 2048, N = 5632, E = 8;
  constexpr int NT = N / BN;
  const int nwg = (M / BM) * NT;
  int bid = blockIdx.x;
  int cpx = nwg >> 3;
  int sid = (bid & 7) * cpx + (bid >> 3);
  int mt = sid / NT, nt = sid % NT;
  int m0 = mt * BM, n0 = nt * BN;
  int tid = threadIdx.x, lane = tid & 63, wid = tid >> 6;
  int wr = (wid >> 1) * 64, wc = (wid & 1) * 64;
  int l16 = lane & 15, lhi = lane >> 4;
  __shared__ short smem[2][2][BM * BK];
  const int s_kc = (tid & 15) * 4;
  const int s_row = tid >> 4;
  const float* Abase = A + (size_t)(m0 + s_row) * K + s_kc;
  f32x4 ar[8], br[8];
  for (int e = 0; e < E; ++e) {
    int rlo = max(m0, seg[e]);
    int rhi = min(m0 + BM, seg[e + 1]);
    if (rlo >= rhi) continue;
    const float* Bbase = B + (size_t)e * N * K + (size_t)(n0 + s_row) * K + s_kc;
    frag_cd acc[4][4];
#pragma unroll
    for (int i = 0; i < 4; ++i)
#pragma unroll
      for (int j = 0; j < 4; ++j) acc[i][j] = (frag_cd){0.f, 0.f, 0.f, 0.f};
    auto issue_loads = [&](int kt) {
#pragma unroll
      for (int i = 0; i < 8; ++i) {
        ar[i] = *(const f32x4*)(Abase + (size_t)i * 16 * K + kt * BK);
        br[i] = *(const f32x4*)(Bbase + (size_t)i * 16 * K + kt * BK);
      }
    };
    auto write_lds = [&](int buf) {
      short* pa = &smem[buf][0][0];
      short* pb = &smem[buf][1][0];
#pragma unroll
      for (int i = 0; i < 8; ++i) {
        int row = s_row + i * 16;
        int off = (row * BK + s_kc) ^ ((row & 7) << 3);
        u32x2 va, vb;
        va[0] = pack_bf2(ar[i][0], ar[i][1]);
        va[1] = pack_bf2(ar[i][2], ar[i][3]);
        vb[0] = pack_bf2(br[i][0], br[i][1]);
        vb[1] = pack_bf2(br[i][2], br[i][3]);
        *(u32x2*)(pa + off) = va;
        *(u32x2*)(pb + off) = vb;
      }
    };
    auto compute = [&](int buf) {
      const short* pa = &smem[buf][0][0];
      const short* pb = &smem[buf][1][0];
#pragma unroll
      for (int ks = 0; ks < 2; ++ks) {
        frag_ab af[4], bf[4];
#pragma unroll
        for (int i = 0; i < 4; ++i) {
          int row = wr + i * 16 + l16;
          af[i] = *(const frag_ab*)(pa + ((row * BK + ks * 32 + lhi * 8) ^ ((row & 7) << 3)));
        }
#pragma unroll
        for (int j = 0; j < 4; ++j) {
          int row = wc + j * 16 + l16;
          bf[j] = *(const frag_ab*)(pb + ((row * BK + ks * 32 + lhi * 8) ^ ((row & 7) << 3)));
        }
#pragma unroll
        for (int i = 0; i < 4; ++i)
#pragma unroll
          for (int j = 0; j < 4; ++j)
            acc[i][j] = __builtin_amdgcn_mfma_f32_16x16x32_bf16(af[i], bf[j], acc[i][j], 0, 0, 0);
      }
    };
    issue_loads(0);
    write_lds(0);
    __syncthreads();
    for (int kt = 0; kt < NKSTEP; ++kt) {
      int cur = kt & 1;
      bool more = (kt + 1 < NKSTEP);
      if (more) issue_loads(kt + 1);
      compute(cur);
      if (more) write_lds(cur ^ 1);
      __syncthreads();
    }
    float sbe = sb[e];
#pragma unroll
    for (int i = 0; i < 4; ++i) {
#pragma unroll
      for (int r = 0; r < 4; ++r) {
        int grow = m0 + wr + i * 16 + lhi * 4 + r;
        if (grow >= rlo && grow < rhi) {
          float s = sa[grow] * sbe;
          float* Crow = C + (size_t)grow * N + n0 + wc;
#pragma unroll
          for (int j = 0; j < 4; ++j) Crow[j * 16 + l16] = acc[i][j][r] * s;
        }
      }
    }
  }
}

extern "C" void kernel_launch(void* const* d_in, const int* in_sizes, int n_in,
                              void* d_out, int out_size, void* d_ws, size_t ws_size,
                              hipStream_t stream) {
  const float* a = (const float*)d_in[0];
  const float* b = (const float*)d_in[1];
  const float* sa = (const float*)d_in[2];
  const float* sb = (const float*)d_in[3];
  const int* seg = (const int*)d_in[4];
  float* out = (float*)d_out;

  constexpr size_t NA = 16384ULL * 2048;       // A elements
  constexpr size_t NB = 8ULL * 5632 * 2048;    // B elements
  constexpr size_t WS_NEED = (NA + NB) * 2;    // 251,658,240 bytes

  dim3 block(256);
  dim3 grid((16384 / BM) * (5632 / BN));  // 5632 blocks

  if (ws_size >= WS_NEED) {
    unsigned short* wa = (unsigned short*)d_ws;
    unsigned short* wb = wa + NA;
    hipLaunchKernelGGL(convert_kernel, dim3(2048), block, 0, stream, a, b, wa, wb);
    hipLaunchKernelGGL(ggemm_bf16, grid, block, 0, stream, wa, wb, sa, sb, seg, out);
  } else {
    hipLaunchKernelGGL(ggemm_f32, grid, block, 0, stream, a, b, sa, sb, seg, out);
  }
}